// Round 3
// baseline (187.898 us; speedup 1.0000x reference)
//
#include <hip/hip_runtime.h>
#include <hip/hip_bf16.h>

// Problem constants
#define DM    1024
#define NH    16
#define DKH   64
#define BB    2
#define SS    2048
#define MROWS (BB*SS)   // 4096

typedef __attribute__((ext_vector_type(8))) short s16x8;
typedef __attribute__((ext_vector_type(4))) float f32x4;
typedef unsigned short u16;

#if __has_builtin(__builtin_amdgcn_exp2f)
#define EXP2(x) __builtin_amdgcn_exp2f(x)
#else
#define EXP2(x) exp2f(x)
#endif

__device__ inline u16 f2b(float f) {
    __hip_bfloat16 h = __float2bfloat16(f);
    return __builtin_bit_cast(u16, h);
}
__device__ inline float b2f(u16 u) {
    return __bfloat162float(__builtin_bit_cast(__hip_bfloat16, u));
}

__device__ inline f32x4 mfma16(s16x8 a, s16x8 b, f32x4 c) {
    return __builtin_amdgcn_mfma_f32_16x16x32_bf16(a, b, c, 0, 0, 0);
}

__device__ inline void gload_lds16(const u16* g, u16* l) {
    __builtin_amdgcn_global_load_lds((const __attribute__((address_space(1))) void*)g,
                                     (__attribute__((address_space(3))) void*)l, 16, 0, 0);
}

// ---------------- prep: fp32 -> bf16 casts ----------------
__global__ void k_prep(const float* __restrict__ x, const float* __restrict__ wq,
                       const float* __restrict__ wk, const float* __restrict__ wv,
                       const float* __restrict__ wo,
                       u16* __restrict__ xb, u16* __restrict__ wqkvb, u16* __restrict__ wob) {
    int64_t i0 = (int64_t)blockIdx.x * blockDim.x + threadIdx.x;
    int64_t strd = (int64_t)gridDim.x * blockDim.x;
    const float4* x4 = (const float4*)x;
    ushort4* xb4 = (ushort4*)xb;
    for (int64_t t = i0; t < (int64_t)MROWS*DM/4; t += strd) {
        float4 v = x4[t];
        xb4[t] = make_ushort4(f2b(v.x), f2b(v.y), f2b(v.z), f2b(v.w));
    }
    const float4* q4 = (const float4*)wq;
    const float4* k4 = (const float4*)wk;
    const float4* v4 = (const float4*)wv;
    const float4* o4 = (const float4*)wo;
    ushort4* w4  = (ushort4*)wqkvb;
    ushort4* wo4 = (ushort4*)wob;
    const int64_t nw4 = (int64_t)DM*DM/4;   // 262144
    for (int64_t t = i0; t < nw4; t += strd) {
        float4 a = q4[t]; w4[t]         = make_ushort4(f2b(a.x), f2b(a.y), f2b(a.z), f2b(a.w));
        float4 b = k4[t]; w4[nw4 + t]   = make_ushort4(f2b(b.x), f2b(b.y), f2b(b.z), f2b(b.w));
        float4 c = v4[t]; w4[2*nw4 + t] = make_ushort4(f2b(c.x), f2b(c.y), f2b(c.z), f2b(c.w));
        float4 d = o4[t]; wo4[t]        = make_ushort4(f2b(d.x), f2b(d.y), f2b(d.z), f2b(d.w));
    }
}

// ---------------- RoPE cos/sin table ----------------
__global__ void k_rope_table(const int* __restrict__ pos, float2* __restrict__ tab) {
    int i = blockIdx.x * blockDim.x + threadIdx.x;  // SS*32 = 65536
    if (i >= SS * 32) return;
    int s = i >> 5, j = i & 31;
    float p = (float)pos[s];
    float freq = powf(10000.0f, -(float)(2 * j) * (1.0f / 64.0f));
    float a = p * freq;
    tab[i] = make_float2(cosf(a), sinf(a));
}

// ---------------- shared 128x128 GEMM mainloop (K=1024, B^T operand) ----------------
__device__ inline void gemm128_loop(const u16* __restrict__ A, const u16* __restrict__ Bt,
                                    int m0, int n0, u16* As, u16* Bs, f32x4 acc[4][4]) {
    const int tid  = threadIdx.x;
    const int lane = tid & 63;
    const int wid  = tid >> 6;
    const int wm = (wid >> 1) << 6;
    const int wn = (wid & 1) << 6;
    const int lr = lane & 15;
    const int lk = (lane >> 4) << 3;

#pragma unroll
    for (int mi = 0; mi < 4; mi++)
#pragma unroll
        for (int ni = 0; ni < 4; ni++) acc[mi][ni] = f32x4{0.f, 0.f, 0.f, 0.f};

    for (int k0 = 0; k0 < 1024; k0 += 32) {
#pragma unroll
        for (int iss = 0; iss < 2; ++iss) {
            int idx = iss * 2048 + tid * 8;
            int row = idx >> 5;
            int col = idx & 31;
            gload_lds16(A  + (int64_t)(m0 + row) * 1024 + (k0 + col), As + idx);
            gload_lds16(Bt + (int64_t)(n0 + row) * 1024 + (k0 + col), Bs + idx);
        }
        __syncthreads();
        s16x8 af[4], bf[4];
#pragma unroll
        for (int mi = 0; mi < 4; mi++)
            af[mi] = *(const s16x8*)(As + (wm + mi * 16 + lr) * 32 + lk);
#pragma unroll
        for (int ni = 0; ni < 4; ni++)
            bf[ni] = *(const s16x8*)(Bs + (wn + ni * 16 + lr) * 32 + lk);
#pragma unroll
        for (int mi = 0; mi < 4; mi++)
#pragma unroll
            for (int ni = 0; ni < 4; ni++)
                acc[mi][ni] = mfma16(af[mi], bf[ni], acc[mi][ni]);
        __syncthreads();
    }
}

// ---------------- QKV projection GEMM: M=4096, N=3072 ----------------
__global__ void __launch_bounds__(256)
k_gemm_qkv(const u16* __restrict__ xb, const u16* __restrict__ wqkvb,
           u16* __restrict__ Qb, u16* __restrict__ Kb, u16* __restrict__ Vb) {
    __shared__ u16 As[4096], Bs[4096];
    int m0 = blockIdx.x * 128, n0 = blockIdx.y * 128;
    f32x4 acc[4][4];
    gemm128_loop(xb, wqkvb, m0, n0, As, Bs, acc);
    const int lane = threadIdx.x & 63, wid = threadIdx.x >> 6;
    const int wm = (wid >> 1) << 6, wn = (wid & 1) << 6;
    const int lr = lane & 15, lg = lane >> 4;
#pragma unroll
    for (int mi = 0; mi < 4; mi++) {
#pragma unroll
        for (int ni = 0; ni < 4; ni++) {
            int gn = n0 + wn + ni * 16 + lr;
            int which = gn >> 10;
            int nn = gn & 1023;
            u16* dst = (which == 0) ? Qb : ((which == 1) ? Kb : Vb);
            int h = nn >> 6, d = nn & 63;
#pragma unroll
            for (int r = 0; r < 4; r++) {
                int gm = m0 + wm + mi * 16 + lg * 4 + r;
                int b = gm >> 11, s = gm & 2047;
                dst[(((int64_t)(b * 16 + h) * 2048) + s) * 64 + d] = f2b(acc[mi][ni][r]);
            }
        }
    }
}

// ---------------- V transpose: Vb[bh][s][d] -> Vt[bh][d][s] ----------------
__global__ void __launch_bounds__(256)
k_vt(const u16* __restrict__ Vb, u16* __restrict__ Vt) {
    __shared__ u16 tile[64][80];
    const int tid = threadIdx.x;
    const int bh = blockIdx.x >> 5;
    const int s0 = (blockIdx.x & 31) << 6;
    const int64_t base = (int64_t)bh * (2048 * 64);
    const int sl = tid >> 2, d0 = (tid & 3) << 4;
    s16x8 v0 = *(const s16x8*)(Vb + base + (int64_t)(s0 + sl) * 64 + d0);
    s16x8 v1 = *(const s16x8*)(Vb + base + (int64_t)(s0 + sl) * 64 + d0 + 8);
    *(s16x8*)&tile[sl][d0] = v0;
    *(s16x8*)&tile[sl][d0 + 8] = v1;
    __syncthreads();
    const int d = tid >> 2, sc0 = (tid & 3) << 4;
    u16 outv[16];
#pragma unroll
    for (int j = 0; j < 16; ++j) outv[j] = tile[sc0 + j][d];
    *(s16x8*)(Vt + base + (int64_t)d * 2048 + s0 + sc0)     = *(s16x8*)&outv[0];
    *(s16x8*)(Vt + base + (int64_t)d * 2048 + s0 + sc0 + 8) = *(s16x8*)&outv[8];
}

// ---------------- RoPE in-place on Q and K; Q gets 0.125*log2(e) folded ----------------
__global__ void k_rope_apply(u16* __restrict__ Qb, u16* __restrict__ Kb,
                             const float2* __restrict__ tab) {
    const float QSC = 0.18033688011112042f;  // (1/8) * log2(e)
    const int64_t np = (int64_t)BB * NH * SS * (DKH / 2);
    int64_t i0 = (int64_t)blockIdx.x * blockDim.x + threadIdx.x;
    int64_t strd = (int64_t)gridDim.x * blockDim.x;
    for (int64_t t = i0; t < 2 * np; t += strd) {
        u16* buf = (t < np) ? Qb : Kb;
        float scl = (t < np) ? QSC : 1.0f;
        int64_t e = (t < np) ? t : t - np;
        int j = (int)(e & 31);
        int s = (int)((e >> 5) & 2047);
        int bh = (int)(e >> 16);
        float2 cs = tab[s * 32 + j];
        u16* p = buf + ((int64_t)bh * 2048 + s) * 64 + 2 * j;
        float xe = b2f(p[0]), xo = b2f(p[1]);
        p[0] = f2b((cs.x * xe - cs.y * xo) * scl);
        p[1] = f2b((cs.y * xe + cs.x * xo) * scl);
    }
}

// ---------------- causal flash attention (no-max softmax, exp2 domain) ----------------
// 4 waves/block = split-KV over ONE 32-row q-chunk; each wave takes tiles t = wid, wid+4, ...
// partials sum linearly (no max tracking) -> LDS tree combine at the end.
__global__ void __launch_bounds__(256)
k_attn(const u16* __restrict__ Q, const u16* __restrict__ K,
       const u16* __restrict__ Vt, u16* __restrict__ O) {
    __shared__ char smem[22528];   // [0,16K): per-wave P (4x4KB); reused after loop for reduce
    const int tid  = threadIdx.x;
    const int lane = tid & 63;
    const int wid  = tid >> 6;
    const int lr = lane & 15;
    const int lg = lane >> 4;
    const int lk = lg * 8;
    const int bh    = blockIdx.x >> 6;    // 0..31
    const int chunk = blockIdx.x & 63;    // 0..63
    const int q0 = chunk << 5;
    const int64_t base = (int64_t)bh * (2048 * 64);
    const u16* Qp = Q  + base;
    const u16* Kp = K  + base;
    const u16* Vp = Vt + base;   // [d][s] layout

    // Q fragments (already scaled by 0.125*log2e in rope)
    s16x8 aq[2][2];
#pragma unroll
    for (int mi = 0; mi < 2; ++mi)
#pragma unroll
        for (int db = 0; db < 2; ++db)
            aq[mi][db] = *(const s16x8*)(Qp + (q0 + mi * 16 + lr) * 64 + db * 32 + lk);

    f32x4 acco[2][4];
    f32x4 accl[2];
#pragma unroll
    for (int mi = 0; mi < 2; ++mi) {
        accl[mi] = f32x4{0.f, 0.f, 0.f, 0.f};
#pragma unroll
        for (int df = 0; df < 4; ++df) acco[mi][df] = f32x4{0.f, 0.f, 0.f, 0.f};
    }
    const s16x8 ones = {(short)0x3F80, (short)0x3F80, (short)0x3F80, (short)0x3F80,
                        (short)0x3F80, (short)0x3F80, (short)0x3F80, (short)0x3F80};
    char* PwB = smem + wid * 4096;
    const int swz = (lr & 7) << 4;

#define P_BLOCK(DIAG)                                                          \
    _Pragma("unroll")                                                          \
    for (int mi = 0; mi < 2; ++mi)                                             \
        _Pragma("unroll")                                                      \
        for (int kb = 0; kb < 4; ++kb)                                         \
            _Pragma("unroll")                                                  \
            for (int r = 0; r < 4; ++r) {                                      \
                int ql = mi * 16 + lg * 4 + r;                                 \
                float s = sc[mi][kb][r];                                       \
                if (DIAG) {                                                    \
                    int kg = k0 + kb * 16 + lr;                                \
                    s = (kg <= q0 + ql) ? s : -3.0e38f;                        \
                }                                                              \
                float p = EXP2(s);                                             \
                int bo = (ql << 7) + ((kb * 16 + lr) << 1);                    \
                *(u16*)(PwB + (bo ^ ((ql & 7) << 4))) = f2b(p);                \
            }

    const int nfull = q0 >> 6;   // index of diagonal tile
    for (int t = wid; t <= nfull; t += 4) {
        const int k0 = t << 6;
        // V fragments first (used last -> latency hidden under QK^T + softmax)
        s16x8 bv[2][4];
#pragma unroll
        for (int kc = 0; kc < 2; ++kc)
#pragma unroll
            for (int df = 0; df < 4; ++df)
                bv[kc][df] = *(const s16x8*)(Vp + (df * 16 + lr) * 2048 + k0 + kc * 32 + lk);
        // K fragments
        s16x8 bk[4][2];
#pragma unroll
        for (int kb = 0; kb < 4; ++kb)
#pragma unroll
            for (int db = 0; db < 2; ++db)
                bk[kb][db] = *(const s16x8*)(Kp + (k0 + kb * 16 + lr) * 64 + db * 32 + lk);
        // QK^T
        f32x4 sc[2][4];
#pragma unroll
        for (int mi = 0; mi < 2; ++mi)
#pragma unroll
            for (int kb = 0; kb < 4; ++kb) {
                sc[mi][kb] = f32x4{0.f, 0.f, 0.f, 0.f};
#pragma unroll
                for (int db = 0; db < 2; ++db)
                    sc[mi][kb] = mfma16(aq[mi][db], bk[kb][db], sc[mi][kb]);
            }
        // exp2 + P write (mask only on diagonal tile)
        if (t == nfull) { P_BLOCK(1) } else { P_BLOCK(0) }
        asm volatile("s_waitcnt lgkmcnt(0)" ::: "memory");
        // PV + row-sum via all-ones MFMA
#pragma unroll
        for (int mi = 0; mi < 2; ++mi)
#pragma unroll
            for (int kc = 0; kc < 2; ++kc) {
                int ro = ((mi * 16 + lr) << 7) + (kc << 6) + (lg << 4);
                s16x8 ap = *(const s16x8*)(PwB + (ro ^ swz));
#pragma unroll
                for (int df = 0; df < 4; ++df)
                    acco[mi][df] = mfma16(ap, bv[kc][df], acco[mi][df]);
                accl[mi] = mfma16(ap, ones, accl[mi]);
            }
    }
#undef P_BLOCK

    // ---- cross-wave combine: partials sum linearly ----
    float* buf0 = (float*)smem;                 // 64*32 f32 (8KB)
    float* buf1 = buf0 + 2048;                  // 64*32 f32 (8KB)
    float* abuf = buf1 + 2048;                  // 3 * 64*8 f32 (6KB)
    __syncthreads();   // all P reads done; safe to reuse smem
    if (wid == 1 || wid == 3) {
        float* b = (wid == 1) ? buf0 : buf1;
#pragma unroll
        for (int mi = 0; mi < 2; ++mi)
#pragma unroll
            for (int df = 0; df < 4; ++df)
#pragma unroll
                for (int r = 0; r < 4; ++r)
                    b[(mi * 16 + df * 4 + r) * 64 + lane] = acco[mi][df][r];
    }
    if (wid >= 1) {
        float* a = abuf + (wid - 1) * 512;
#pragma unroll
        for (int mi = 0; mi < 2; ++mi)
#pragma unroll
            for (int r = 0; r < 4; ++r)
                a[(mi * 4 + r) * 64 + lane] = accl[mi][r];
    }
    __syncthreads();
    if (wid == 0 || wid == 2) {
        const float* b = (wid == 0) ? buf0 : buf1;
#pragma unroll
        for (int mi = 0; mi < 2; ++mi)
#pragma unroll
            for (int df = 0; df < 4; ++df)
#pragma unroll
                for (int r = 0; r < 4; ++r)
                    acco[mi][df][r] += b[(mi * 16 + df * 4 + r) * 64 + lane];
    }
    __syncthreads();
    if (wid == 2) {
#pragma unroll
        for (int mi = 0; mi < 2; ++mi)
#pragma unroll
            for (int df = 0; df < 4; ++df)
#pragma unroll
                for (int r = 0; r < 4; ++r)
                    buf0[(mi * 16 + df * 4 + r) * 64 + lane] = acco[mi][df][r];
    }
    __syncthreads();
    if (wid == 0) {
#pragma unroll
        for (int mi = 0; mi < 2; ++mi) {
#pragma unroll
            for (int df = 0; df < 4; ++df)
#pragma unroll
                for (int r = 0; r < 4; ++r)
                    acco[mi][df][r] += buf0[(mi * 16 + df * 4 + r) * 64 + lane];
#pragma unroll
            for (int r = 0; r < 4; ++r)
                accl[mi][r] += abuf[(mi * 4 + r) * 64 + lane]
                             + abuf[512 + (mi * 4 + r) * 64 + lane]
                             + abuf[1024 + (mi * 4 + r) * 64 + lane];
        }
        const int b = bh >> 4, h = bh & 15;
#pragma unroll
        for (int mi = 0; mi < 2; ++mi) {
            float inv[4];
#pragma unroll
            for (int r = 0; r < 4; ++r) inv[r] = 1.0f / accl[mi][r];
#pragma unroll
            for (int df = 0; df < 4; ++df)
#pragma unroll
                for (int r = 0; r < 4; ++r) {
                    const int s = q0 + mi * 16 + lg * 4 + r;
                    const int d = df * 16 + lr;
                    O[(((int64_t)(b * 2048 + s)) * 16 + h) * 64 + d] = f2b(acco[mi][df][r] * inv[r]);
                }
        }
    }
}

// ---------------- output projection GEMM: M=4096, N=1024, fp32 out ----------------
__global__ void __launch_bounds__(256)
k_gemm_out(const u16* __restrict__ Ob, const u16* __restrict__ wob, float* __restrict__ out) {
    __shared__ u16 As[4096], Bs[4096];
    int m0 = blockIdx.x * 128, n0 = blockIdx.y * 128;
    f32x4 acc[4][4];
    gemm128_loop(Ob, wob, m0, n0, As, Bs, acc);
    const int lane = threadIdx.x & 63, wid = threadIdx.x >> 6;
    const int wm = (wid >> 1) << 6, wn = (wid & 1) << 6;
    const int lr = lane & 15, lg = lane >> 4;
#pragma unroll
    for (int mi = 0; mi < 4; mi++)
#pragma unroll
        for (int ni = 0; ni < 4; ni++) {
            int gn = n0 + wn + ni * 16 + lr;
#pragma unroll
            for (int r = 0; r < 4; r++) {
                int gm = m0 + wm + mi * 16 + lg * 4 + r;
                out[(int64_t)gm * 1024 + gn] = acc[mi][ni][r];
            }
        }
}

extern "C" void kernel_launch(void* const* d_in, const int* in_sizes, int n_in,
                              void* d_out, int out_size, void* d_ws, size_t ws_size,
                              hipStream_t stream) {
    const float* x  = (const float*)d_in[0];
    const int* pos  = (const int*)d_in[1];
    const float* wq = (const float*)d_in[2];
    const float* wk = (const float*)d_in[3];
    const float* wv = (const float*)d_in[4];
    const float* wo = (const float*)d_in[5];
    float* out = (float*)d_out;

    char* w = (char*)d_ws;
    u16* xb    = (u16*)w;    w += (size_t)MROWS * DM * 2;        // 8 MB
    u16* wqkvb = (u16*)w;    w += (size_t)3 * DM * DM * 2;       // 6 MB
    u16* wob   = (u16*)w;    w += (size_t)DM * DM * 2;           // 2 MB
    float2* tab = (float2*)w; w += (size_t)SS * 32 * sizeof(float2); // 512 KB
    u16* Qb = (u16*)w;       w += (size_t)MROWS * DM * 2;        // 8 MB
    u16* Kb = (u16*)w;       w += (size_t)MROWS * DM * 2;        // 8 MB
    u16* Vb = (u16*)w;       w += (size_t)MROWS * DM * 2;        // 8 MB
    u16* Ob = (u16*)w;                                           // 8 MB
    u16* Vt = xb;   // xb dead after k_gemm_qkv; reuse for transposed V

    k_prep<<<dim3(1024), dim3(256), 0, stream>>>(x, wq, wk, wv, wo, xb, wqkvb, wob);
    k_rope_table<<<dim3(256), dim3(256), 0, stream>>>(pos, tab);
    k_gemm_qkv<<<dim3(32, 24), dim3(256), 0, stream>>>(xb, wqkvb, Qb, Kb, Vb);
    k_vt<<<dim3(1024), dim3(256), 0, stream>>>(Vb, Vt);
    k_rope_apply<<<dim3(2048), dim3(256), 0, stream>>>(Qb, Kb, tab);
    k_attn<<<dim3(2048), dim3(256), 0, stream>>>(Qb, Kb, Vt, Ob);
    k_gemm_out<<<dim3(32, 8), dim3(256), 0, stream>>>(Ob, wob, out);
}

// Round 4
// 152.154 us; speedup vs baseline: 1.2349x; 1.2349x over previous
//
#include <hip/hip_runtime.h>
#include <hip/hip_bf16.h>

// Problem constants
#define DM    1024
#define NH    16
#define DKH   64
#define BB    2
#define SS    2048
#define MROWS (BB*SS)   // 4096

typedef __attribute__((ext_vector_type(8))) short s16x8;
typedef __attribute__((ext_vector_type(4))) float f32x4;
typedef unsigned short u16;

#if __has_builtin(__builtin_amdgcn_exp2f)
#define EXP2(x) __builtin_amdgcn_exp2f(x)
#else
#define EXP2(x) exp2f(x)
#endif

__device__ inline u16 f2b(float f) {
    __hip_bfloat16 h = __float2bfloat16(f);
    return __builtin_bit_cast(u16, h);
}
__device__ inline float b2f(u16 u) {
    return __bfloat162float(__builtin_bit_cast(__hip_bfloat16, u));
}

__device__ inline f32x4 mfma16(s16x8 a, s16x8 b, f32x4 c) {
    return __builtin_amdgcn_mfma_f32_16x16x32_bf16(a, b, c, 0, 0, 0);
}

__device__ inline void gload_lds16(const u16* g, u16* l) {
    __builtin_amdgcn_global_load_lds((const __attribute__((address_space(1))) void*)g,
                                     (__attribute__((address_space(3))) void*)l, 16, 0, 0);
}

// ---------------- prep: fp32 -> bf16 casts ----------------
__global__ void k_prep(const float* __restrict__ x, const float* __restrict__ wq,
                       const float* __restrict__ wk, const float* __restrict__ wv,
                       const float* __restrict__ wo,
                       u16* __restrict__ xb, u16* __restrict__ wqkvb, u16* __restrict__ wob) {
    int64_t i0 = (int64_t)blockIdx.x * blockDim.x + threadIdx.x;
    int64_t strd = (int64_t)gridDim.x * blockDim.x;
    const float4* x4 = (const float4*)x;
    ushort4* xb4 = (ushort4*)xb;
    for (int64_t t = i0; t < (int64_t)MROWS*DM/4; t += strd) {
        float4 v = x4[t];
        xb4[t] = make_ushort4(f2b(v.x), f2b(v.y), f2b(v.z), f2b(v.w));
    }
    const float4* q4 = (const float4*)wq;
    const float4* k4 = (const float4*)wk;
    const float4* v4 = (const float4*)wv;
    const float4* o4 = (const float4*)wo;
    ushort4* w4  = (ushort4*)wqkvb;
    ushort4* wo4 = (ushort4*)wob;
    const int64_t nw4 = (int64_t)DM*DM/4;   // 262144
    for (int64_t t = i0; t < nw4; t += strd) {
        float4 a = q4[t]; w4[t]         = make_ushort4(f2b(a.x), f2b(a.y), f2b(a.z), f2b(a.w));
        float4 b = k4[t]; w4[nw4 + t]   = make_ushort4(f2b(b.x), f2b(b.y), f2b(b.z), f2b(b.w));
        float4 c = v4[t]; w4[2*nw4 + t] = make_ushort4(f2b(c.x), f2b(c.y), f2b(c.z), f2b(c.w));
        float4 d = o4[t]; wo4[t]        = make_ushort4(f2b(d.x), f2b(d.y), f2b(d.z), f2b(d.w));
    }
}

// ---------------- RoPE cos/sin table ----------------
__global__ void k_rope_table(const int* __restrict__ pos, float2* __restrict__ tab) {
    int i = blockIdx.x * blockDim.x + threadIdx.x;  // SS*32 = 65536
    if (i >= SS * 32) return;
    int s = i >> 5, j = i & 31;
    float p = (float)pos[s];
    float freq = powf(10000.0f, -(float)(2 * j) * (1.0f / 64.0f));
    float a = p * freq;
    tab[i] = make_float2(cosf(a), sinf(a));
}

// ---------------- shared 128x128 GEMM mainloop (K=1024, B^T operand) ----------------
__device__ inline void gemm128_loop(const u16* __restrict__ A, const u16* __restrict__ Bt,
                                    int m0, int n0, u16* As, u16* Bs, f32x4 acc[4][4]) {
    const int tid  = threadIdx.x;
    const int lane = tid & 63;
    const int wid  = tid >> 6;
    const int wm = (wid >> 1) << 6;
    const int wn = (wid & 1) << 6;
    const int lr = lane & 15;
    const int lk = (lane >> 4) << 3;

#pragma unroll
    for (int mi = 0; mi < 4; mi++)
#pragma unroll
        for (int ni = 0; ni < 4; ni++) acc[mi][ni] = f32x4{0.f, 0.f, 0.f, 0.f};

    for (int k0 = 0; k0 < 1024; k0 += 32) {
#pragma unroll
        for (int iss = 0; iss < 2; ++iss) {
            int idx = iss * 2048 + tid * 8;
            int row = idx >> 5;
            int col = idx & 31;
            gload_lds16(A  + (int64_t)(m0 + row) * 1024 + (k0 + col), As + idx);
            gload_lds16(Bt + (int64_t)(n0 + row) * 1024 + (k0 + col), Bs + idx);
        }
        __syncthreads();
        s16x8 af[4], bf[4];
#pragma unroll
        for (int mi = 0; mi < 4; mi++)
            af[mi] = *(const s16x8*)(As + (wm + mi * 16 + lr) * 32 + lk);
#pragma unroll
        for (int ni = 0; ni < 4; ni++)
            bf[ni] = *(const s16x8*)(Bs + (wn + ni * 16 + lr) * 32 + lk);
#pragma unroll
        for (int mi = 0; mi < 4; mi++)
#pragma unroll
            for (int ni = 0; ni < 4; ni++)
                acc[mi][ni] = mfma16(af[mi], bf[ni], acc[mi][ni]);
        __syncthreads();
    }
}

// ---------------- QKV projection GEMM: M=4096, N=3072 ----------------
__global__ void __launch_bounds__(256)
k_gemm_qkv(const u16* __restrict__ xb, const u16* __restrict__ wqkvb,
           u16* __restrict__ Qb, u16* __restrict__ Kb, u16* __restrict__ Vb) {
    __shared__ u16 As[4096], Bs[4096];
    int m0 = blockIdx.x * 128, n0 = blockIdx.y * 128;
    f32x4 acc[4][4];
    gemm128_loop(xb, wqkvb, m0, n0, As, Bs, acc);
    const int lane = threadIdx.x & 63, wid = threadIdx.x >> 6;
    const int wm = (wid >> 1) << 6, wn = (wid & 1) << 6;
    const int lr = lane & 15, lg = lane >> 4;
#pragma unroll
    for (int mi = 0; mi < 4; mi++) {
#pragma unroll
        for (int ni = 0; ni < 4; ni++) {
            int gn = n0 + wn + ni * 16 + lr;
            int which = gn >> 10;
            int nn = gn & 1023;
            u16* dst = (which == 0) ? Qb : ((which == 1) ? Kb : Vb);
            int h = nn >> 6, d = nn & 63;
#pragma unroll
            for (int r = 0; r < 4; r++) {
                int gm = m0 + wm + mi * 16 + lg * 4 + r;
                int b = gm >> 11, s = gm & 2047;
                dst[(((int64_t)(b * 16 + h) * 2048) + s) * 64 + d] = f2b(acc[mi][ni][r]);
            }
        }
    }
}

// ---------------- V transpose: Vb[bh][s][d] -> Vt[bh][d][s] ----------------
__global__ void __launch_bounds__(256)
k_vt(const u16* __restrict__ Vb, u16* __restrict__ Vt) {
    __shared__ u16 tile[64][80];
    const int tid = threadIdx.x;
    const int bh = blockIdx.x >> 5;
    const int s0 = (blockIdx.x & 31) << 6;
    const int64_t base = (int64_t)bh * (2048 * 64);
    const int sl = tid >> 2, d0 = (tid & 3) << 4;
    s16x8 v0 = *(const s16x8*)(Vb + base + (int64_t)(s0 + sl) * 64 + d0);
    s16x8 v1 = *(const s16x8*)(Vb + base + (int64_t)(s0 + sl) * 64 + d0 + 8);
    *(s16x8*)&tile[sl][d0] = v0;
    *(s16x8*)&tile[sl][d0 + 8] = v1;
    __syncthreads();
    const int d = tid >> 2, sc0 = (tid & 3) << 4;
    u16 outv[16];
#pragma unroll
    for (int j = 0; j < 16; ++j) outv[j] = tile[sc0 + j][d];
    *(s16x8*)(Vt + base + (int64_t)d * 2048 + s0 + sc0)     = *(s16x8*)&outv[0];
    *(s16x8*)(Vt + base + (int64_t)d * 2048 + s0 + sc0 + 8) = *(s16x8*)&outv[8];
}

// ---------------- RoPE in-place on Q and K; Q gets 0.125*log2(e) folded ----------------
__global__ void k_rope_apply(u16* __restrict__ Qb, u16* __restrict__ Kb,
                             const float2* __restrict__ tab) {
    const float QSC = 0.18033688011112042f;  // (1/8) * log2(e)
    const int64_t np = (int64_t)BB * NH * SS * (DKH / 2);
    int64_t i0 = (int64_t)blockIdx.x * blockDim.x + threadIdx.x;
    int64_t strd = (int64_t)gridDim.x * blockDim.x;
    for (int64_t t = i0; t < 2 * np; t += strd) {
        u16* buf = (t < np) ? Qb : Kb;
        float scl = (t < np) ? QSC : 1.0f;
        int64_t e = (t < np) ? t : t - np;
        int j = (int)(e & 31);
        int s = (int)((e >> 5) & 2047);
        int bh = (int)(e >> 16);
        float2 cs = tab[s * 32 + j];
        u16* p = buf + ((int64_t)bh * 2048 + s) * 64 + 2 * j;
        float xe = b2f(p[0]), xo = b2f(p[1]);
        p[0] = f2b((cs.x * xe - cs.y * xo) * scl);
        p[1] = f2b((cs.y * xe + cs.x * xo) * scl);
    }
}

// ---------------- causal flash attention (no-max softmax, exp2 domain) ----------------
// ONE wave per block (64 threads): each block owns one (bh, 32-row chunk); sequential
// KV-tile loop, zero barriers, private 4KB P-LDS. LPT dispatch (big chunks first),
// bh->XCD affinity via blockIdx&31 with stride-32 groups.
__global__ void __launch_bounds__(64)
k_attn(const u16* __restrict__ Q, const u16* __restrict__ K,
       const u16* __restrict__ Vt, u16* __restrict__ O) {
    __shared__ char PwB[4096];   // 32x64 bf16, XOR-swizzled
    const int lane = threadIdx.x;
    const int lr = lane & 15;
    const int lg = lane >> 4;
    const int lk = lg * 8;
    const int chunk = 63 - (blockIdx.x >> 5);   // LPT: heavy chunks dispatch first
    const int bh    = blockIdx.x & 31;          // bh b -> XCD b%8 (stride 32 == 0 mod 8)
    const int q0 = chunk << 5;
    const int64_t base = (int64_t)bh * (2048 * 64);
    const u16* Qp = Q  + base;
    const u16* Kp = K  + base;
    const u16* Vp = Vt + base;   // [d][s] layout

    // Q fragments (already scaled by 0.125*log2e in rope)
    s16x8 aq[2][2];
#pragma unroll
    for (int mi = 0; mi < 2; ++mi)
#pragma unroll
        for (int db = 0; db < 2; ++db)
            aq[mi][db] = *(const s16x8*)(Qp + (q0 + mi * 16 + lr) * 64 + db * 32 + lk);

    f32x4 acco[2][4];
    f32x4 accl[2];
#pragma unroll
    for (int mi = 0; mi < 2; ++mi) {
        accl[mi] = f32x4{0.f, 0.f, 0.f, 0.f};
#pragma unroll
        for (int df = 0; df < 4; ++df) acco[mi][df] = f32x4{0.f, 0.f, 0.f, 0.f};
    }
    const s16x8 ones = {(short)0x3F80, (short)0x3F80, (short)0x3F80, (short)0x3F80,
                        (short)0x3F80, (short)0x3F80, (short)0x3F80, (short)0x3F80};
    const int swz = (lr & 7) << 4;

#define P_BLOCK(DIAG)                                                          \
    _Pragma("unroll")                                                          \
    for (int mi = 0; mi < 2; ++mi)                                             \
        _Pragma("unroll")                                                      \
        for (int kb = 0; kb < 4; ++kb)                                         \
            _Pragma("unroll")                                                  \
            for (int r = 0; r < 4; ++r) {                                      \
                int ql = mi * 16 + lg * 4 + r;                                 \
                float s = sc[mi][kb][r];                                       \
                if (DIAG) {                                                    \
                    int kg = k0 + kb * 16 + lr;                                \
                    s = (kg <= q0 + ql) ? s : -3.0e38f;                        \
                }                                                              \
                float p = EXP2(s);                                             \
                int bo = (ql << 7) + ((kb * 16 + lr) << 1);                    \
                *(u16*)(PwB + (bo ^ ((ql & 7) << 4))) = f2b(p);                \
            }

    const int nfull = q0 >> 6;   // index of diagonal tile
    for (int t = 0; t <= nfull; ++t) {
        const int k0 = t << 6;
        // V fragments first (used last -> latency hidden under QK^T + softmax)
        s16x8 bv[2][4];
#pragma unroll
        for (int kc = 0; kc < 2; ++kc)
#pragma unroll
            for (int df = 0; df < 4; ++df)
                bv[kc][df] = *(const s16x8*)(Vp + (df * 16 + lr) * 2048 + k0 + kc * 32 + lk);
        // K fragments
        s16x8 bk[4][2];
#pragma unroll
        for (int kb = 0; kb < 4; ++kb)
#pragma unroll
            for (int db = 0; db < 2; ++db)
                bk[kb][db] = *(const s16x8*)(Kp + (k0 + kb * 16 + lr) * 64 + db * 32 + lk);
        // QK^T
        f32x4 sc[2][4];
#pragma unroll
        for (int mi = 0; mi < 2; ++mi)
#pragma unroll
            for (int kb = 0; kb < 4; ++kb) {
                sc[mi][kb] = f32x4{0.f, 0.f, 0.f, 0.f};
#pragma unroll
                for (int db = 0; db < 2; ++db)
                    sc[mi][kb] = mfma16(aq[mi][db], bk[kb][db], sc[mi][kb]);
            }
        // exp2 + P write (mask only on diagonal tile)
        if (t == nfull) { P_BLOCK(1) } else { P_BLOCK(0) }
        asm volatile("s_waitcnt lgkmcnt(0)" ::: "memory");
        // PV + row-sum via all-ones MFMA
#pragma unroll
        for (int mi = 0; mi < 2; ++mi)
#pragma unroll
            for (int kc = 0; kc < 2; ++kc) {
                int ro = ((mi * 16 + lr) << 7) + (kc << 6) + (lg << 4);
                s16x8 ap = *(const s16x8*)(PwB + (ro ^ swz));
#pragma unroll
                for (int df = 0; df < 4; ++df)
                    acco[mi][df] = mfma16(ap, bv[kc][df], acco[mi][df]);
                accl[mi] = mfma16(ap, ones, accl[mi]);
            }
    }
#undef P_BLOCK

    const int b = bh >> 4, h = bh & 15;
#pragma unroll
    for (int mi = 0; mi < 2; ++mi) {
        float inv[4];
#pragma unroll
        for (int r = 0; r < 4; ++r) inv[r] = 1.0f / accl[mi][r];
#pragma unroll
        for (int df = 0; df < 4; ++df)
#pragma unroll
            for (int r = 0; r < 4; ++r) {
                const int s = q0 + mi * 16 + lg * 4 + r;
                const int d = df * 16 + lr;
                O[(((int64_t)(b * 2048 + s)) * 16 + h) * 64 + d] = f2b(acco[mi][df][r] * inv[r]);
            }
    }
}

// ---------------- output projection GEMM: M=4096, N=1024, fp32 out ----------------
__global__ void __launch_bounds__(256)
k_gemm_out(const u16* __restrict__ Ob, const u16* __restrict__ wob, float* __restrict__ out) {
    __shared__ u16 As[4096], Bs[4096];
    int m0 = blockIdx.x * 128, n0 = blockIdx.y * 128;
    f32x4 acc[4][4];
    gemm128_loop(Ob, wob, m0, n0, As, Bs, acc);
    const int lane = threadIdx.x & 63, wid = threadIdx.x >> 6;
    const int wm = (wid >> 1) << 6, wn = (wid & 1) << 6;
    const int lr = lane & 15, lg = lane >> 4;
#pragma unroll
    for (int mi = 0; mi < 4; mi++)
#pragma unroll
        for (int ni = 0; ni < 4; ni++) {
            int gn = n0 + wn + ni * 16 + lr;
#pragma unroll
            for (int r = 0; r < 4; r++) {
                int gm = m0 + wm + mi * 16 + lg * 4 + r;
                out[(int64_t)gm * 1024 + gn] = acc[mi][ni][r];
            }
        }
}

extern "C" void kernel_launch(void* const* d_in, const int* in_sizes, int n_in,
                              void* d_out, int out_size, void* d_ws, size_t ws_size,
                              hipStream_t stream) {
    const float* x  = (const float*)d_in[0];
    const int* pos  = (const int*)d_in[1];
    const float* wq = (const float*)d_in[2];
    const float* wk = (const float*)d_in[3];
    const float* wv = (const float*)d_in[4];
    const float* wo = (const float*)d_in[5];
    float* out = (float*)d_out;

    char* w = (char*)d_ws;
    u16* xb    = (u16*)w;    w += (size_t)MROWS * DM * 2;        // 8 MB
    u16* wqkvb = (u16*)w;    w += (size_t)3 * DM * DM * 2;       // 6 MB
    u16* wob   = (u16*)w;    w += (size_t)DM * DM * 2;           // 2 MB
    float2* tab = (float2*)w; w += (size_t)SS * 32 * sizeof(float2); // 512 KB
    u16* Qb = (u16*)w;       w += (size_t)MROWS * DM * 2;        // 8 MB
    u16* Kb = (u16*)w;       w += (size_t)MROWS * DM * 2;        // 8 MB
    u16* Vb = (u16*)w;       w += (size_t)MROWS * DM * 2;        // 8 MB
    u16* Ob = (u16*)w;                                           // 8 MB
    u16* Vt = xb;   // xb dead after k_gemm_qkv; reuse for transposed V

    k_prep<<<dim3(1024), dim3(256), 0, stream>>>(x, wq, wk, wv, wo, xb, wqkvb, wob);
    k_rope_table<<<dim3(256), dim3(256), 0, stream>>>(pos, tab);
    k_gemm_qkv<<<dim3(32, 24), dim3(256), 0, stream>>>(xb, wqkvb, Qb, Kb, Vb);
    k_vt<<<dim3(1024), dim3(256), 0, stream>>>(Vb, Vt);
    k_rope_apply<<<dim3(2048), dim3(256), 0, stream>>>(Qb, Kb, tab);
    k_attn<<<dim3(2048), dim3(64), 0, stream>>>(Qb, Kb, Vt, Ob);
    k_gemm_out<<<dim3(32, 8), dim3(256), 0, stream>>>(Ob, wob, out);
}

// Round 5
// 147.708 us; speedup vs baseline: 1.2721x; 1.0301x over previous
//
#include <hip/hip_runtime.h>
#include <hip/hip_bf16.h>

// Problem constants
#define DM    1024
#define NH    16
#define DKH   64
#define BB    2
#define SS    2048
#define MROWS (BB*SS)   // 4096

typedef __attribute__((ext_vector_type(8))) short s16x8;
typedef __attribute__((ext_vector_type(4))) float f32x4;
typedef unsigned short u16;

#if __has_builtin(__builtin_amdgcn_exp2f)
#define EXP2(x) __builtin_amdgcn_exp2f(x)
#else
#define EXP2(x) exp2f(x)
#endif

__device__ inline u16 f2b(float f) {
    __hip_bfloat16 h = __float2bfloat16(f);
    return __builtin_bit_cast(u16, h);
}
__device__ inline float b2f(u16 u) {
    return __bfloat162float(__builtin_bit_cast(__hip_bfloat16, u));
}

__device__ inline f32x4 mfma16(s16x8 a, s16x8 b, f32x4 c) {
    return __builtin_amdgcn_mfma_f32_16x16x32_bf16(a, b, c, 0, 0, 0);
}

__device__ inline void gload_lds16(const u16* g, u16* l) {
    __builtin_amdgcn_global_load_lds((const __attribute__((address_space(1))) void*)g,
                                     (__attribute__((address_space(3))) void*)l, 16, 0, 0);
}

// ---------------- prep: fp32 -> bf16 casts ----------------
__global__ void k_prep(const float* __restrict__ x, const float* __restrict__ wq,
                       const float* __restrict__ wk, const float* __restrict__ wv,
                       const float* __restrict__ wo,
                       u16* __restrict__ xb, u16* __restrict__ wqkvb, u16* __restrict__ wob) {
    int64_t i0 = (int64_t)blockIdx.x * blockDim.x + threadIdx.x;
    int64_t strd = (int64_t)gridDim.x * blockDim.x;
    const float4* x4 = (const float4*)x;
    ushort4* xb4 = (ushort4*)xb;
    for (int64_t t = i0; t < (int64_t)MROWS*DM/4; t += strd) {
        float4 v = x4[t];
        xb4[t] = make_ushort4(f2b(v.x), f2b(v.y), f2b(v.z), f2b(v.w));
    }
    const float4* q4 = (const float4*)wq;
    const float4* k4 = (const float4*)wk;
    const float4* v4 = (const float4*)wv;
    const float4* o4 = (const float4*)wo;
    ushort4* w4  = (ushort4*)wqkvb;
    ushort4* wo4 = (ushort4*)wob;
    const int64_t nw4 = (int64_t)DM*DM/4;   // 262144
    for (int64_t t = i0; t < nw4; t += strd) {
        float4 a = q4[t]; w4[t]         = make_ushort4(f2b(a.x), f2b(a.y), f2b(a.z), f2b(a.w));
        float4 b = k4[t]; w4[nw4 + t]   = make_ushort4(f2b(b.x), f2b(b.y), f2b(b.z), f2b(b.w));
        float4 c = v4[t]; w4[2*nw4 + t] = make_ushort4(f2b(c.x), f2b(c.y), f2b(c.z), f2b(c.w));
        float4 d = o4[t]; wo4[t]        = make_ushort4(f2b(d.x), f2b(d.y), f2b(d.z), f2b(d.w));
    }
}

// ---------------- RoPE cos/sin table ----------------
__global__ void k_rope_table(const int* __restrict__ pos, float2* __restrict__ tab) {
    int i = blockIdx.x * blockDim.x + threadIdx.x;  // SS*32 = 65536
    if (i >= SS * 32) return;
    int s = i >> 5, j = i & 31;
    float p = (float)pos[s];
    float freq = powf(10000.0f, -(float)(2 * j) * (1.0f / 64.0f));
    float a = p * freq;
    tab[i] = make_float2(cosf(a), sinf(a));
}

// ---------------- shared 128x128 GEMM mainloop (K=1024, B^T operand) ----------------
__device__ inline void gemm128_loop(const u16* __restrict__ A, const u16* __restrict__ Bt,
                                    int m0, int n0, u16* As, u16* Bs, f32x4 acc[4][4]) {
    const int tid  = threadIdx.x;
    const int lane = tid & 63;
    const int wid  = tid >> 6;
    const int wm = (wid >> 1) << 6;
    const int wn = (wid & 1) << 6;
    const int lr = lane & 15;
    const int lk = (lane >> 4) << 3;

#pragma unroll
    for (int mi = 0; mi < 4; mi++)
#pragma unroll
        for (int ni = 0; ni < 4; ni++) acc[mi][ni] = f32x4{0.f, 0.f, 0.f, 0.f};

    for (int k0 = 0; k0 < 1024; k0 += 32) {
#pragma unroll
        for (int iss = 0; iss < 2; ++iss) {
            int idx = iss * 2048 + tid * 8;
            int row = idx >> 5;
            int col = idx & 31;
            gload_lds16(A  + (int64_t)(m0 + row) * 1024 + (k0 + col), As + idx);
            gload_lds16(Bt + (int64_t)(n0 + row) * 1024 + (k0 + col), Bs + idx);
        }
        __syncthreads();
        s16x8 af[4], bf[4];
#pragma unroll
        for (int mi = 0; mi < 4; mi++)
            af[mi] = *(const s16x8*)(As + (wm + mi * 16 + lr) * 32 + lk);
#pragma unroll
        for (int ni = 0; ni < 4; ni++)
            bf[ni] = *(const s16x8*)(Bs + (wn + ni * 16 + lr) * 32 + lk);
#pragma unroll
        for (int mi = 0; mi < 4; mi++)
#pragma unroll
            for (int ni = 0; ni < 4; ni++)
                acc[mi][ni] = mfma16(af[mi], bf[ni], acc[mi][ni]);
        __syncthreads();
    }
}

// ---------------- QKV projection GEMM with fused RoPE + V-transpose epilogue ----------------
// Q/K: rope applied to f32 acc via shfl-pair; Q scaled by 0.125*log2e.
// V: written directly transposed to Vt[bh][d][s] as packed 8B stores.
__global__ void __launch_bounds__(256)
k_gemm_qkv(const u16* __restrict__ xb, const u16* __restrict__ wqkvb,
           const float2* __restrict__ tab,
           u16* __restrict__ Qb, u16* __restrict__ Kb, u16* __restrict__ Vt) {
    __shared__ u16 As[4096], Bs[4096];
    int m0 = blockIdx.x * 128, n0 = blockIdx.y * 128;
    f32x4 acc[4][4];
    gemm128_loop(xb, wqkvb, m0, n0, As, Bs, acc);
    const float QSC = 0.18033688011112042f;  // (1/8) * log2(e)
    const int lane = threadIdx.x & 63, wid = threadIdx.x >> 6;
    const int wm = (wid >> 1) << 6, wn = (wid & 1) << 6;
    const int lr = lane & 15, lg = lane >> 4;
    const bool evenlane = (lr & 1) == 0;
#pragma unroll
    for (int mi = 0; mi < 4; mi++) {
        const int gm0 = m0 + wm + mi * 16 + lg * 4;
        const int b = gm0 >> 11;
        const int s0 = gm0 & 2047;
#pragma unroll
        for (int ni = 0; ni < 4; ni++) {
            int gn = n0 + wn + ni * 16 + lr;
            int which = gn >> 10;
            int nn = gn & 1023;
            int h = nn >> 6, d = nn & 63;
            if (which == 2) {
                ushort4 pk;
                pk.x = f2b(acc[mi][ni][0]);
                pk.y = f2b(acc[mi][ni][1]);
                pk.z = f2b(acc[mi][ni][2]);
                pk.w = f2b(acc[mi][ni][3]);
                *(ushort4*)(Vt + ((int64_t)(b * 16 + h)) * (2048 * 64)
                               + (int64_t)d * 2048 + s0) = pk;
            } else {
                u16* dst = (which == 0) ? Qb : Kb;
                float scl = (which == 0) ? QSC : 1.0f;
                int j = d >> 1;
#pragma unroll
                for (int r = 0; r < 4; r++) {
                    float v = acc[mi][ni][r];
                    float partner = __shfl_xor(v, 1, 64);
                    float2 cs = tab[(s0 + r) * 32 + j];
                    float outv = evenlane ? (cs.x * v - cs.y * partner)
                                          : (cs.y * partner + cs.x * v);
                    dst[(((int64_t)(b * 16 + h)) * 2048 + (s0 + r)) * 64 + d] =
                        f2b(outv * scl);
                }
            }
        }
    }
}

// ---------------- causal flash attention (no-max softmax, exp2 domain) ----------------
// ONE wave per block; 32 q-rows per wave; KV tile = 64 keys; zero barriers.
// 2-deep software pipeline: K reg-prefetch, V reg double-buffer, P LDS double-buffer
// (PV of tile t-1 overlaps exp/VALU of tile t). LPT dispatch + bh->XCD affinity.
__global__ void __launch_bounds__(64, 2)
k_attn(const u16* __restrict__ Q, const u16* __restrict__ K,
       const u16* __restrict__ Vt, u16* __restrict__ O) {
    __shared__ char Pbuf[2][4096];   // 32x64 bf16 each, XOR-swizzled
    const int lane = threadIdx.x;
    const int lr = lane & 15;
    const int lg = lane >> 4;
    const int lk = lg * 8;
    const int chunk = 63 - (blockIdx.x >> 5);   // LPT: heavy chunks first
    const int bh    = blockIdx.x & 31;          // bh -> XCD bh%8
    const int q0 = chunk << 5;
    const int64_t base = (int64_t)bh * (2048 * 64);
    const u16* Qp = Q  + base;
    const u16* Kp = K  + base;
    const u16* Vp = Vt + base;   // [d][s] layout

    s16x8 aq[2][2];
#pragma unroll
    for (int mi = 0; mi < 2; ++mi)
#pragma unroll
        for (int db = 0; db < 2; ++db)
            aq[mi][db] = *(const s16x8*)(Qp + (q0 + mi * 16 + lr) * 64 + db * 32 + lk);

    f32x4 acco[2][4];
    f32x4 accl[2];
#pragma unroll
    for (int mi = 0; mi < 2; ++mi) {
        accl[mi] = f32x4{0.f, 0.f, 0.f, 0.f};
#pragma unroll
        for (int df = 0; df < 4; ++df) acco[mi][df] = f32x4{0.f, 0.f, 0.f, 0.f};
    }
    const s16x8 ones = {(short)0x3F80, (short)0x3F80, (short)0x3F80, (short)0x3F80,
                        (short)0x3F80, (short)0x3F80, (short)0x3F80, (short)0x3F80};
    const int swz = (lr & 7) << 4;
    const int nfull = q0 >> 6;
    char* P0 = (char*)&Pbuf[0][0];
    char* P1 = (char*)&Pbuf[1][0];

    s16x8 bk[4][2], bva[2][4], bvb[2][4];
#pragma unroll
    for (int kb = 0; kb < 4; ++kb)
#pragma unroll
        for (int db = 0; db < 2; ++db)
            bk[kb][db] = *(const s16x8*)(Kp + (kb * 16 + lr) * 64 + db * 32 + lk);
#pragma unroll
    for (int kc = 0; kc < 2; ++kc)
#pragma unroll
        for (int df = 0; df < 4; ++df)
            bva[kc][df] = *(const s16x8*)(Vp + (df * 16 + lr) * 2048 + kc * 32 + lk);

#define EXP_BLOCK(PDST, DIAG, K0)                                              \
    _Pragma("unroll")                                                          \
    for (int mi = 0; mi < 2; ++mi)                                             \
        _Pragma("unroll")                                                      \
        for (int kb = 0; kb < 4; ++kb)                                         \
            _Pragma("unroll")                                                  \
            for (int r = 0; r < 4; ++r) {                                      \
                int ql = mi * 16 + lg * 4 + r;                                 \
                float sv = sc[mi][kb][r];                                      \
                if (DIAG) {                                                    \
                    int kg = (K0) + kb * 16 + lr;                              \
                    sv = (kg <= q0 + ql) ? sv : -3.0e38f;                      \
                }                                                              \
                float pp = EXP2(sv);                                           \
                int bo = (ql << 7) + ((kb * 16 + lr) << 1);                    \
                *(u16*)((PDST) + (bo ^ ((ql & 7) << 4))) = f2b(pp);            \
            }

#define TILE_BODY(TQ, PCUR, PPREV, BVO)                                        \
    {                                                                          \
        const int k0v = (TQ) << 6;                                             \
        f32x4 sc[2][4];                                                        \
        _Pragma("unroll")                                                      \
        for (int mi = 0; mi < 2; ++mi)                                         \
            _Pragma("unroll")                                                  \
            for (int kb = 0; kb < 4; ++kb) {                                   \
                sc[mi][kb] = f32x4{0.f, 0.f, 0.f, 0.f};                        \
                _Pragma("unroll")                                              \
                for (int db = 0; db < 2; ++db)                                 \
                    sc[mi][kb] = mfma16(aq[mi][db], bk[kb][db], sc[mi][kb]);   \
            }                                                                  \
        if ((TQ) + 1 <= nfull) {                                               \
            const int kn = k0v + 64;                                           \
            _Pragma("unroll")                                                  \
            for (int kb = 0; kb < 4; ++kb)                                     \
                _Pragma("unroll")                                              \
                for (int db = 0; db < 2; ++db)                                 \
                    bk[kb][db] = *(const s16x8*)(Kp + (kn + kb * 16 + lr) * 64 \
                                                 + db * 32 + lk);              \
        }                                                                      \
        s16x8 ap[2][2];                                                        \
        if ((TQ) > 0) {                                                        \
            _Pragma("unroll")                                                  \
            for (int mi = 0; mi < 2; ++mi)                                     \
                _Pragma("unroll")                                              \
                for (int kc = 0; kc < 2; ++kc) {                               \
                    int ro = ((mi * 16 + lr) << 7) + (kc << 6) + (lg << 4);    \
                    ap[mi][kc] = *(const s16x8*)((PPREV) + (ro ^ swz));        \
                }                                                              \
        }                                                                      \
        if ((TQ) == nfull) { EXP_BLOCK(PCUR, 1, k0v) }                         \
        else               { EXP_BLOCK(PCUR, 0, k0v) }                         \
        if ((TQ) > 0) {                                                        \
            _Pragma("unroll")                                                  \
            for (int mi = 0; mi < 2; ++mi)                                     \
                _Pragma("unroll")                                              \
                for (int kc = 0; kc < 2; ++kc) {                               \
                    _Pragma("unroll")                                          \
                    for (int df = 0; df < 4; ++df)                             \
                        acco[mi][df] = mfma16(ap[mi][kc], (BVO)[kc][df],       \
                                              acco[mi][df]);                   \
                    accl[mi] = mfma16(ap[mi][kc], ones, accl[mi]);             \
                }                                                              \
        }                                                                      \
        if ((TQ) + 1 <= nfull) {                                               \
            const int kn = k0v + 64;                                           \
            _Pragma("unroll")                                                  \
            for (int kc = 0; kc < 2; ++kc)                                     \
                _Pragma("unroll")                                              \
                for (int df = 0; df < 4; ++df)                                 \
                    (BVO)[kc][df] = *(const s16x8*)(Vp + (df * 16 + lr) * 2048 \
                                                    + kn + kc * 32 + lk);      \
        }                                                                      \
    }

    for (int t = 0; t <= nfull; t += 2) {
        TILE_BODY(t, P0, P1, bvb)
        if (t + 1 <= nfull) TILE_BODY(t + 1, P1, P0, bva)
    }

#define PV_FIN(PP, BV)                                                         \
    _Pragma("unroll")                                                          \
    for (int mi = 0; mi < 2; ++mi)                                             \
        _Pragma("unroll")                                                      \
        for (int kc = 0; kc < 2; ++kc) {                                       \
            int ro = ((mi * 16 + lr) << 7) + (kc << 6) + (lg << 4);            \
            s16x8 ap = *(const s16x8*)((PP) + (ro ^ swz));                     \
            _Pragma("unroll")                                                  \
            for (int df = 0; df < 4; ++df)                                     \
                acco[mi][df] = mfma16(ap, (BV)[kc][df], acco[mi][df]);         \
            accl[mi] = mfma16(ap, ones, accl[mi]);                             \
        }

    // final tile's PV (tile nfull)
    if (nfull & 1) { PV_FIN(P1, bvb) } else { PV_FIN(P0, bva) }
#undef PV_FIN
#undef TILE_BODY
#undef EXP_BLOCK

    const int b = bh >> 4, h = bh & 15;
#pragma unroll
    for (int mi = 0; mi < 2; ++mi) {
        float inv[4];
#pragma unroll
        for (int r = 0; r < 4; ++r) inv[r] = 1.0f / accl[mi][r];
#pragma unroll
        for (int df = 0; df < 4; ++df)
#pragma unroll
            for (int r = 0; r < 4; ++r) {
                const int s = q0 + mi * 16 + lg * 4 + r;
                const int d = df * 16 + lr;
                O[(((int64_t)(b * 2048 + s)) * 16 + h) * 64 + d] = f2b(acco[mi][df][r] * inv[r]);
            }
    }
}

// ---------------- output projection GEMM: M=4096, N=1024, fp32 out ----------------
__global__ void __launch_bounds__(256)
k_gemm_out(const u16* __restrict__ Ob, const u16* __restrict__ wob, float* __restrict__ out) {
    __shared__ u16 As[4096], Bs[4096];
    int m0 = blockIdx.x * 128, n0 = blockIdx.y * 128;
    f32x4 acc[4][4];
    gemm128_loop(Ob, wob, m0, n0, As, Bs, acc);
    const int lane = threadIdx.x & 63, wid = threadIdx.x >> 6;
    const int wm = (wid >> 1) << 6, wn = (wid & 1) << 6;
    const int lr = lane & 15, lg = lane >> 4;
#pragma unroll
    for (int mi = 0; mi < 4; mi++)
#pragma unroll
        for (int ni = 0; ni < 4; ni++) {
            int gn = n0 + wn + ni * 16 + lr;
#pragma unroll
            for (int r = 0; r < 4; r++) {
                int gm = m0 + wm + mi * 16 + lg * 4 + r;
                out[(int64_t)gm * 1024 + gn] = acc[mi][ni][r];
            }
        }
}

extern "C" void kernel_launch(void* const* d_in, const int* in_sizes, int n_in,
                              void* d_out, int out_size, void* d_ws, size_t ws_size,
                              hipStream_t stream) {
    const float* x  = (const float*)d_in[0];
    const int* pos  = (const int*)d_in[1];
    const float* wq = (const float*)d_in[2];
    const float* wk = (const float*)d_in[3];
    const float* wv = (const float*)d_in[4];
    const float* wo = (const float*)d_in[5];
    float* out = (float*)d_out;

    char* w = (char*)d_ws;
    u16* xb    = (u16*)w;    w += (size_t)MROWS * DM * 2;        // 8 MB
    u16* wqkvb = (u16*)w;    w += (size_t)3 * DM * DM * 2;       // 6 MB
    u16* wob   = (u16*)w;    w += (size_t)DM * DM * 2;           // 2 MB
    float2* tab = (float2*)w; w += (size_t)SS * 32 * sizeof(float2); // 512 KB
    u16* Qb = (u16*)w;       w += (size_t)MROWS * DM * 2;        // 8 MB
    u16* Kb = (u16*)w;       w += (size_t)MROWS * DM * 2;        // 8 MB
    u16* Vt = (u16*)w;       w += (size_t)MROWS * DM * 2;        // 8 MB
    u16* Ob = (u16*)w;                                           // 8 MB

    k_prep<<<dim3(1024), dim3(256), 0, stream>>>(x, wq, wk, wv, wo, xb, wqkvb, wob);
    k_rope_table<<<dim3(256), dim3(256), 0, stream>>>(pos, tab);
    k_gemm_qkv<<<dim3(32, 24), dim3(256), 0, stream>>>(xb, wqkvb, tab, Qb, Kb, Vt);
    k_attn<<<dim3(2048), dim3(64), 0, stream>>>(Qb, Kb, Vt, Ob);
    k_gemm_out<<<dim3(32, 8), dim3(256), 0, stream>>>(Ob, wob, out);
}